// Round 3
// baseline (410.497 us; speedup 1.0000x reference)
//
#include <hip/hip_runtime.h>

#define NN 100000
#define EE 1600000
#define NPAD 100096          // NN rounded up to 128-row blocks (782*128)
#define NBKT 196             // ceil(NN/512) scatter buckets
#define CAP 9216             // bucket capacity (mean 8192, sigma 90 -> 11 sigma)
#define BN_EPS 1e-5f

using f32x4  = __attribute__((ext_vector_type(4))) float;
using f32x8  = __attribute__((ext_vector_type(8))) float;
using s16x8  = __attribute__((ext_vector_type(8))) short;
using u16x4  = __attribute__((ext_vector_type(4))) unsigned short;
using u16x8  = __attribute__((ext_vector_type(8))) unsigned short;
using bf16x8 = __attribute__((ext_vector_type(8))) __bf16;
typedef unsigned short ushort_t;

__device__ __forceinline__ float bf2f(ushort_t b) {
  union { unsigned u; float f; } x; x.u = ((unsigned)b) << 16; return x.f;
}
__device__ __forceinline__ ushort_t f2bf(float f) {
  union { float f; unsigned u; } x; x.f = f;
  unsigned r = x.u + 0x7fffu + ((x.u >> 16) & 1u);   // RN-even; no NaNs in pipeline
  return (ushort_t)(r >> 16);
}

// ---------------- CSR build: fixed-capacity two-level scatter ----------------
__global__ __launch_bounds__(256) void k_bin(const int* __restrict__ src,
                                             const int* __restrict__ dst,
                                             int* __restrict__ gbc,
                                             unsigned* __restrict__ ebuf) {
  __shared__ int hist[NBKT];
  int t = threadIdx.x;
  for (int i = t; i < NBKT; i += 256) hist[i] = 0;
  __syncthreads();
  int base = blockIdx.x * 4096;
  int s[16], d[16];
#pragma unroll
  for (int j = 0; j < 16; j++) {
    int e = base + j * 256 + t;
    if (e < EE) { s[j] = src[e]; d[j] = dst[e]; atomicAdd(&hist[d[j] >> 9], 1); }
    else d[j] = -1;
  }
  __syncthreads();
  for (int i = t; i < NBKT; i += 256) {
    int c = hist[i];
    hist[i] = c ? atomicAdd(&gbc[i], c) : 0;   // reserve in-bucket run
  }
  __syncthreads();
#pragma unroll
  for (int j = 0; j < 16; j++) {
    if (d[j] >= 0) {
      int bkt = d[j] >> 9;
      int pos = atomicAdd(&hist[bkt], 1);
      if (pos < CAP)                            // safety clamp (never hit here)
        ebuf[(size_t)bkt * CAP + pos] = (unsigned)s[j] | ((unsigned)(d[j] & 511) << 17);
    }
  }
}

// scan bucket counts -> ebase; rowptr[NN]=EE; zero BN stats
__global__ void k_bktscan(const int* __restrict__ gbc, int* __restrict__ ebase,
                          int* __restrict__ rowptr, float* __restrict__ stats) {
  __shared__ int sd[256];
  int t = threadIdx.x;
#pragma unroll
  for (int k = 0; k < 3; k++) stats[t + 256 * k] = 0.f;   // 768 floats
  int c = (t < NBKT) ? min(gbc[t], CAP) : 0;
  sd[t] = c; __syncthreads();
  for (int off = 1; off < 256; off <<= 1) {
    int x = 0;
    if (t >= off) x = sd[t - off];
    __syncthreads();
    sd[t] += x;
    __syncthreads();
  }
  if (t < NBKT) ebase[t] = sd[t] - c;          // exclusive
  if (t == NBKT - 1) rowptr[NN] = sd[t];       // == EE
}

// per bucket: LDS degree hist -> LDS scan -> rowptr + fine scatter (L2-resident window)
__global__ __launch_bounds__(256) void k_fine(const unsigned* __restrict__ ebuf,
                                              const int* __restrict__ gbc,
                                              const int* __restrict__ ebase,
                                              int* __restrict__ rowptr,
                                              int* __restrict__ csr) {
  __shared__ int dcur[512];
  __shared__ int sd[256];
  int b = blockIdx.x, t = threadIdx.x;
  int cnt = min(gbc[b], CAP);
  int eb = ebase[b];
  const unsigned* eb_p = ebuf + (size_t)b * CAP;
  dcur[t] = 0; dcur[t + 256] = 0;
  __syncthreads();
  for (int e = t; e < cnt; e += 256)
    atomicAdd(&dcur[(eb_p[e] >> 17) & 511], 1);
  __syncthreads();
  int a0 = dcur[2 * t], a1 = dcur[2 * t + 1];
  int ps = a0 + a1;
  sd[t] = ps; __syncthreads();
  for (int off = 1; off < 256; off <<= 1) {
    int x = 0;
    if (t >= off) x = sd[t - off];
    __syncthreads();
    sd[t] += x;
    __syncthreads();
  }
  int g0 = eb + sd[t] - ps;                    // global csr start for local node 2t
  dcur[2 * t] = g0; dcur[2 * t + 1] = g0 + a0;
  int n = (b << 9) + 2 * t;
  if (n < NN) rowptr[n] = g0;
  if (n + 1 < NN) rowptr[n + 1] = g0 + a0;
  __syncthreads();
  for (int e = t; e < cnt; e += 256) {
    unsigned v = eb_p[e];
    int pos = atomicAdd(&dcur[(v >> 17) & 511], 1);
    csr[pos] = (int)(v & 0x1FFFFu);
  }
}

// ---------------- merged prep: x->bf16 (blocks 0..6249) + W swizzle (6250..6261) ----
__global__ void k_prep(const float* __restrict__ x, ushort_t* __restrict__ hb,
                       const float* __restrict__ W1s, const float* __restrict__ W2s,
                       ushort_t* __restrict__ wf) {
  int b = blockIdx.x;
  if (b < 6250) {
    int i = b * 256 + threadIdx.x;   // each handles 4 elems of x
    f32x4 v = *(const f32x4*)(x + (size_t)i * 4);
    u16x4 o;
#pragma unroll
    for (int m = 0; m < 4; m++) o[m] = f2bf(v[m]);
    *(u16x4*)(hb + (size_t)i * 4) = o;
  } else {
    int gid = (b - 6250) * 256 + threadIdx.x;
    if (gid >= 3072) return;                  // 6 mats * 2u * 4t * 64 lanes
    int mat = gid >> 9, rem = gid & 511;
    int u = rem >> 8, t = (rem >> 6) & 3, lane = rem & 63;
    const float* W = ((mat & 1) ? W2s : W1s) + (mat >> 1) * 4096;
    ushort_t* o = wf + gid * 8;
#pragma unroll
    for (int j = 0; j < 8; j++) {
      int k = u * 32 + (lane >> 4) * 8 + j;
      int n = t * 16 + (lane & 15);
      o[j] = f2bf(W[k * 64 + n]);
    }
  }
}

// ---------------- fused aggregate + mlp1 (v3: two-node interleaved pipelines) ----
// 512 threads = 8 waves; block owns 128 nodes. Each 8-lane group owns TWO
// adjacent nodes with separate accumulators: the two idx->rows->acc chains
// issue back-to-back so their LLC latencies overlap (2x memory-level
// parallelism per wave; forces ~2x register state so the compiler cannot
// serialize it back down). Every chunk is clamp-masked (weights in {0,1},
// exact) -> no serial scalar tail. Phase 2: 8 waves x (16 rows x 64 cols).
__global__ __launch_bounds__(512) void k_aggmlp1(
    const ushort_t* __restrict__ hb, const int* __restrict__ rowptr,
    const int* __restrict__ csr, const ushort_t* __restrict__ wfrag,
    const float* __restrict__ b1, ushort_t* __restrict__ zb,
    float* __restrict__ stats) {
  __shared__ __align__(16) ushort_t sw[128 * 72];  // stride 72 elems (16B-aligned rows)
  __shared__ float lsum[64], lsq[64];
  int tid = threadIdx.x;
  if (tid < 64) lsum[tid] = 0.f;
  else if (tid < 128) lsq[tid - 64] = 0.f;
  int wv = tid >> 6, lane = tid & 63;
  int grp = lane >> 3, fl = lane & 7;
  int nl0 = (wv * 8 + grp) * 2;                 // local rows 0..127 (pair)
  int n0 = blockIdx.x * 128 + nl0;
  int n1 = n0 + 1;
  const ushort_t* hbase = hb + fl * 8;

  f32x8 A = {0, 0, 0, 0, 0, 0, 0, 0};
  f32x8 B = {0, 0, 0, 0, 0, 0, 0, 0};
  int e0 = 0, c0 = 0, e1 = 0, c1 = 0;
  if (n0 < NN) {
    u16x8 sr0 = *(const u16x8*)(hbase + (size_t)n0 * 64);
    int p0 = rowptr[n0], p1 = rowptr[n0 + 1];
    e0 = p0; c0 = p1 - p0;
    if (n1 < NN) {
      u16x8 sr1 = *(const u16x8*)(hbase + (size_t)n1 * 64);
      int p2 = rowptr[n1 + 1];
      e1 = p1; c1 = p2 - p1;
#pragma unroll
      for (int m = 0; m < 8; m++) B[m] = bf2f(sr1[m]);
    }
#pragma unroll
    for (int m = 0; m < 8; m++) A[m] = bf2f(sr0[m]);
  }

  while (c0 > 0 || c1 > 0) {
    bool d0 = c0 > 0, d1 = c1 > 0;
    int i0 = 0, i1 = 0, i2 = 0, i3 = 0, i4 = 0, i5 = 0, i6 = 0, i7 = 0;
    int j0 = 0, j1 = 0, j2 = 0, j3 = 0, j4 = 0, j5 = 0, j6 = 0, j7 = 0;
    if (d0) {
      int last = e0 + min(c0, 8) - 1;
      i0 = csr[e0];
      i1 = csr[min(e0 + 1, last)]; i2 = csr[min(e0 + 2, last)];
      i3 = csr[min(e0 + 3, last)]; i4 = csr[min(e0 + 4, last)];
      i5 = csr[min(e0 + 5, last)]; i6 = csr[min(e0 + 6, last)];
      i7 = csr[min(e0 + 7, last)];
    }
    if (d1) {
      int last = e1 + min(c1, 8) - 1;
      j0 = csr[e1];
      j1 = csr[min(e1 + 1, last)]; j2 = csr[min(e1 + 2, last)];
      j3 = csr[min(e1 + 3, last)]; j4 = csr[min(e1 + 4, last)];
      j5 = csr[min(e1 + 5, last)]; j6 = csr[min(e1 + 6, last)];
      j7 = csr[min(e1 + 7, last)];
    }
    u16x8 ra0, ra1, ra2, ra3, ra4, ra5, ra6, ra7;
    u16x8 rb0, rb1, rb2, rb3, rb4, rb5, rb6, rb7;
    if (d0) {
      ra0 = *(const u16x8*)(hbase + (size_t)i0 * 64);
      ra1 = *(const u16x8*)(hbase + (size_t)i1 * 64);
      ra2 = *(const u16x8*)(hbase + (size_t)i2 * 64);
      ra3 = *(const u16x8*)(hbase + (size_t)i3 * 64);
      ra4 = *(const u16x8*)(hbase + (size_t)i4 * 64);
      ra5 = *(const u16x8*)(hbase + (size_t)i5 * 64);
      ra6 = *(const u16x8*)(hbase + (size_t)i6 * 64);
      ra7 = *(const u16x8*)(hbase + (size_t)i7 * 64);
    }
    if (d1) {
      rb0 = *(const u16x8*)(hbase + (size_t)j0 * 64);
      rb1 = *(const u16x8*)(hbase + (size_t)j1 * 64);
      rb2 = *(const u16x8*)(hbase + (size_t)j2 * 64);
      rb3 = *(const u16x8*)(hbase + (size_t)j3 * 64);
      rb4 = *(const u16x8*)(hbase + (size_t)j4 * 64);
      rb5 = *(const u16x8*)(hbase + (size_t)j5 * 64);
      rb6 = *(const u16x8*)(hbase + (size_t)j6 * 64);
      rb7 = *(const u16x8*)(hbase + (size_t)j7 * 64);
    }
    if (d0) {
      float w1 = (c0 > 1) ? 1.f : 0.f, w2 = (c0 > 2) ? 1.f : 0.f;
      float w3 = (c0 > 3) ? 1.f : 0.f, w4 = (c0 > 4) ? 1.f : 0.f;
      float w5 = (c0 > 5) ? 1.f : 0.f, w6 = (c0 > 6) ? 1.f : 0.f;
      float w7 = (c0 > 7) ? 1.f : 0.f;
#pragma unroll
      for (int m = 0; m < 8; m++) A[m] += bf2f(ra0[m]);
#pragma unroll
      for (int m = 0; m < 8; m++) A[m] += w1 * bf2f(ra1[m]);
#pragma unroll
      for (int m = 0; m < 8; m++) A[m] += w2 * bf2f(ra2[m]);
#pragma unroll
      for (int m = 0; m < 8; m++) A[m] += w3 * bf2f(ra3[m]);
#pragma unroll
      for (int m = 0; m < 8; m++) A[m] += w4 * bf2f(ra4[m]);
#pragma unroll
      for (int m = 0; m < 8; m++) A[m] += w5 * bf2f(ra5[m]);
#pragma unroll
      for (int m = 0; m < 8; m++) A[m] += w6 * bf2f(ra6[m]);
#pragma unroll
      for (int m = 0; m < 8; m++) A[m] += w7 * bf2f(ra7[m]);
      e0 += 8; c0 -= 8;
    }
    if (d1) {
      float w1 = (c1 > 1) ? 1.f : 0.f, w2 = (c1 > 2) ? 1.f : 0.f;
      float w3 = (c1 > 3) ? 1.f : 0.f, w4 = (c1 > 4) ? 1.f : 0.f;
      float w5 = (c1 > 5) ? 1.f : 0.f, w6 = (c1 > 6) ? 1.f : 0.f;
      float w7 = (c1 > 7) ? 1.f : 0.f;
#pragma unroll
      for (int m = 0; m < 8; m++) B[m] += bf2f(rb0[m]);
#pragma unroll
      for (int m = 0; m < 8; m++) B[m] += w1 * bf2f(rb1[m]);
#pragma unroll
      for (int m = 0; m < 8; m++) B[m] += w2 * bf2f(rb2[m]);
#pragma unroll
      for (int m = 0; m < 8; m++) B[m] += w3 * bf2f(rb3[m]);
#pragma unroll
      for (int m = 0; m < 8; m++) B[m] += w4 * bf2f(rb4[m]);
#pragma unroll
      for (int m = 0; m < 8; m++) B[m] += w5 * bf2f(rb5[m]);
#pragma unroll
      for (int m = 0; m < 8; m++) B[m] += w6 * bf2f(rb6[m]);
#pragma unroll
      for (int m = 0; m < 8; m++) B[m] += w7 * bf2f(rb7[m]);
      e1 += 8; c1 -= 8;
    }
  }
  {
    u16x8 oa, ob;
#pragma unroll
    for (int m = 0; m < 8; m++) { oa[m] = f2bf(A[m]); ob[m] = f2bf(B[m]); }
    *(u16x8*)(sw + nl0 * 72 + fl * 8) = oa;
    *(u16x8*)(sw + (nl0 + 1) * 72 + fl * 8) = ob;
  }
  __syncthreads();

  // ---- phase 2: MFMA; each wave = 16 rows x 64 cols (8 waves cover 128 rows) ----
  {
    int quad = lane >> 4, lo = lane & 15;
    int row0 = blockIdx.x * 128 + wv * 16;
    s16x8 bfr[2][4];
#pragma unroll
    for (int u = 0; u < 2; u++)
#pragma unroll
      for (int t = 0; t < 4; t++)
        bfr[u][t] = *(const s16x8*)(wfrag + (size_t)((u * 4 + t) * 64 + lane) * 8);

    f32x4 acc[4] = {};
#pragma unroll
    for (int u = 0; u < 2; u++) {
      bf16x8 af = *(const bf16x8*)(sw + (wv * 16 + lo) * 72 + u * 32 + quad * 8);
#pragma unroll
      for (int t = 0; t < 4; t++)
        acc[t] = __builtin_amdgcn_mfma_f32_16x16x32_bf16(
            af, __builtin_bit_cast(bf16x8, bfr[u][t]), acc[t], 0, 0, 0);
    }
    // C/D layout: col = t*16 + lo, row = row0 + quad*4 + r
#pragma unroll
    for (int t = 0; t < 4; t++) {
      int col = t * 16 + lo;
      float bb = b1[col];
      float s1 = 0.f, s2 = 0.f;
#pragma unroll
      for (int r = 0; r < 4; r++) {
        int row = row0 + quad * 4 + r;
        if (row < NN) {
          float v = acc[t][r] + bb;
          zb[(size_t)row * 64 + col] = f2bf(v);
          s1 += v; s2 += v * v;
        }
      }
      atomicAdd(&lsum[col], s1);
      atomicAdd(&lsq[col], s2);
    }
  }
  __syncthreads();
  if (tid < 64) {
    atomicAdd(&stats[tid], lsum[tid]);
    atomicAdd(&stats[64 + tid], lsq[tid]);
  }
}

// relu_out=1 (L0,L1): hb16 = relu( relu(zb*a+c)@W2 + b2 )
// relu_out=0 (L2):    h -> out+200000 (fp32) AND out[0..2N) = h@Wd + bd (fused decoder)
// v2: 512 threads / 128 rows per block (2x per-block MLP, half the blocks).
__global__ __launch_bounds__(512) void k_mlp2(
    const ushort_t* __restrict__ zb, const float* __restrict__ stats,
    const float* __restrict__ gamma, const float* __restrict__ beta,
    const ushort_t* __restrict__ wfrag, const float* __restrict__ b2,
    ushort_t* __restrict__ hb, float* __restrict__ out,
    const float* __restrict__ Wd, const float* __restrict__ bd, int relu_out) {
  __shared__ __align__(16) ushort_t sw[128 * 72];
  __shared__ float abn[64], cbn[64];
  int tid = threadIdx.x;
  if (tid < 64) {   // fused BN finalize
    float inv = 1.f / (float)NN;
    float mu = stats[tid] * inv;
    float var = stats[64 + tid] * inv - mu * mu;
    float a = gamma[tid] * rsqrtf(var + BN_EPS);
    abn[tid] = a;
    cbn[tid] = beta[tid] - mu * a;
  }
  __syncthreads();
  {   // phase 1: BN affine + ReLU on bf16 z -> bf16 tile in LDS (128 rows)
    int r = tid >> 2, c0 = (tid & 3) * 16;
    size_t grow = (size_t)blockIdx.x * 128 + r;    // < NPAD; padded rows masked at store
#pragma unroll
    for (int jj = 0; jj < 16; jj += 8) {
      s16x8 zv = *(const s16x8*)(zb + grow * 64 + c0 + jj);
      f32x4 av0 = *(const f32x4*)(abn + c0 + jj);
      f32x4 av1 = *(const f32x4*)(abn + c0 + jj + 4);
      f32x4 cv0 = *(const f32x4*)(cbn + c0 + jj);
      f32x4 cv1 = *(const f32x4*)(cbn + c0 + jj + 4);
#pragma unroll
      for (int m = 0; m < 4; m++) {
        float v0 = fmaxf(bf2f((ushort_t)zv[m]) * av0[m] + cv0[m], 0.f);
        float v1 = fmaxf(bf2f((ushort_t)zv[m + 4]) * av1[m] + cv1[m], 0.f);
        sw[r * 72 + c0 + jj + m] = f2bf(v0);
        sw[r * 72 + c0 + jj + m + 4] = f2bf(v1);
      }
    }
  }
  __syncthreads();
  int wv = tid >> 6, lane = tid & 63;
  int quad = lane >> 4, lo = lane & 15;

  s16x8 bfr[2][4];
#pragma unroll
  for (int u = 0; u < 2; u++)
#pragma unroll
    for (int t = 0; t < 4; t++)
      bfr[u][t] = *(const s16x8*)(wfrag + (size_t)((u * 4 + t) * 64 + lane) * 8);

  f32x4 acc[4] = {};
#pragma unroll
  for (int u = 0; u < 2; u++) {
    bf16x8 af = *(const bf16x8*)(sw + (wv * 16 + lo) * 72 + u * 32 + quad * 8);
#pragma unroll
    for (int t = 0; t < 4; t++)
      acc[t] = __builtin_amdgcn_mfma_f32_16x16x32_bf16(
          af, __builtin_bit_cast(bf16x8, bfr[u][t]), acc[t], 0, 0, 0);
  }
  int row0 = blockIdx.x * 128 + wv * 16;
  float bbv[4];
#pragma unroll
  for (int t = 0; t < 4; t++) bbv[t] = b2[t * 16 + lo];

  if (relu_out) {
#pragma unroll
    for (int t = 0; t < 4; t++) {
      int col = t * 16 + lo;
#pragma unroll
      for (int r = 0; r < 4; r++) {
        int row = row0 + quad * 4 + r;
        if (row < NN)
          hb[(size_t)row * 64 + col] = f2bf(fmaxf(acc[t][r] + bbv[t], 0.f));
      }
    }
  } else {
    float* outh = out + (size_t)NN * 2;
    float wd0[4], wd1[4];
#pragma unroll
    for (int t = 0; t < 4; t++) {
      wd0[t] = Wd[(t * 16 + lo) * 2];
      wd1[t] = Wd[(t * 16 + lo) * 2 + 1];
    }
    float bd0 = bd[0], bd1 = bd[1];
#pragma unroll
    for (int t = 0; t < 4; t++) {
      int col = t * 16 + lo;
#pragma unroll
      for (int r = 0; r < 4; r++) {
        int row = row0 + quad * 4 + r;
        if (row < NN) outh[(size_t)row * 64 + col] = acc[t][r] + bbv[t];
      }
    }
#pragma unroll
    for (int r = 0; r < 4; r++) {
      float p0 = 0.f, p1 = 0.f;
#pragma unroll
      for (int t = 0; t < 4; t++) {
        float v = acc[t][r] + bbv[t];
        p0 += v * wd0[t]; p1 += v * wd1[t];
      }
#pragma unroll
      for (int o = 1; o < 16; o <<= 1) {   // reduce across the 16 lanes of the quad
        p0 += __shfl_xor(p0, o);
        p1 += __shfl_xor(p1, o);
      }
      int row = row0 + quad * 4 + r;
      if (lo == 0 && row < NN) {
        out[(size_t)row * 2 + 0] = p0 + bd0;
        out[(size_t)row * 2 + 1] = p1 + bd1;
      }
    }
  }
}

extern "C" void kernel_launch(void* const* d_in, const int* in_sizes, int n_in,
                              void* d_out, int out_size, void* d_ws, size_t ws_size,
                              hipStream_t stream) {
  (void)in_sizes; (void)n_in; (void)out_size; (void)ws_size;
  const float* x   = (const float*)d_in[0];
  const int*   ei  = (const int*)d_in[1];
  const float* W1s = (const float*)d_in[2];
  const float* b1s = (const float*)d_in[3];
  const float* gms = (const float*)d_in[4];
  const float* bts = (const float*)d_in[5];
  const float* W2s = (const float*)d_in[6];
  const float* b2s = (const float*)d_in[7];
  const float* Wd  = (const float*)d_in[8];
  const float* bd  = (const float*)d_in[9];
  float* out = (float*)d_out;
  const int* src = ei;
  const int* dst = ei + EE;

  char* w = (char*)d_ws;
  size_t off = 0;
  auto alloc = [&](size_t b) { char* p = w + off; off += (b + 255) & ~(size_t)255; return p; };
  ushort_t* zb     = (ushort_t*)alloc((size_t)NPAD * 64 * 2);   // 12.8 MB (ebuf aliases)
  ushort_t* hb16   = (ushort_t*)alloc((size_t)NPAD * 64 * 2);   // 12.8 MB bf16 rows
  int*      csr    = (int*)alloc((size_t)EE * 4);               // 6.4 MB
  int*      rowptr = (int*)alloc((size_t)(NN + 1) * 4);
  int*      gbc    = (int*)alloc((size_t)NBKT * 4);
  int*      ebase  = (int*)alloc((size_t)NBKT * 4);
  float*    stats  = (float*)alloc(768 * 4);                    // 3 x [sum|sq|spare]
  ushort_t* wf     = (ushort_t*)alloc((size_t)6 * 512 * 8 * 2); // swizzled W frags
  unsigned* ebuf   = (unsigned*)zb;  // 196*9216*4 = 7.2 MB, used pre-mlp only

  hipMemsetAsync(gbc, 0, (size_t)NBKT * 4, stream);
  k_bin    <<<(EE + 4095) / 4096, 256, 0, stream>>>(src, dst, gbc, ebuf);
  k_bktscan<<<1, 256, 0, stream>>>(gbc, ebase, rowptr, stats);
  k_fine   <<<NBKT, 256, 0, stream>>>(ebuf, gbc, ebase, rowptr, csr);
  k_prep   <<<6262, 256, 0, stream>>>(x, hb16, W1s, W2s, wf);

  int nblk = (NN + 127) / 128;   // 782
  for (int L = 0; L < 3; L++) {
    k_aggmlp1<<<nblk, 512, 0, stream>>>(hb16, rowptr, csr,
                                        wf + (size_t)(L * 2) * 4096,
                                        b1s + L * 64, zb, stats + L * 256);
    k_mlp2<<<nblk, 512, 0, stream>>>(zb, stats + L * 256,
                                     gms + L * 64, bts + L * 64,
                                     wf + (size_t)(L * 2 + 1) * 4096,
                                     b2s + L * 64, hb16, out, Wd, bd,
                                     (L < 2) ? 1 : 0);
  }
}

// Round 4
// 378.727 us; speedup vs baseline: 1.0839x; 1.0839x over previous
//
#include <hip/hip_runtime.h>

#define NN 100000
#define EE 1600000
#define NPAD 100032          // NN rounded up to 64-row MFMA tiles
#define NBKT 196             // ceil(NN/512) scatter buckets
#define CAP 9216             // bucket capacity (mean 8192, sigma 90 -> 11 sigma)
#define BN_EPS 1e-5f

using f32x4  = __attribute__((ext_vector_type(4))) float;
using f32x8  = __attribute__((ext_vector_type(8))) float;
using s16x8  = __attribute__((ext_vector_type(8))) short;
using u16x4  = __attribute__((ext_vector_type(4))) unsigned short;
using u16x8  = __attribute__((ext_vector_type(8))) unsigned short;
using bf16x8 = __attribute__((ext_vector_type(8))) __bf16;
typedef unsigned short ushort_t;

__device__ __forceinline__ float bf2f(ushort_t b) {
  union { unsigned u; float f; } x; x.u = ((unsigned)b) << 16; return x.f;
}
__device__ __forceinline__ ushort_t f2bf(float f) {
  union { float f; unsigned u; } x; x.f = f;
  unsigned r = x.u + 0x7fffu + ((x.u >> 16) & 1u);   // RN-even; no NaNs in pipeline
  return (ushort_t)(r >> 16);
}

// async global->LDS: per-lane global src, wave-uniform LDS base; lane i lands
// at base + i*16 (m104/m108 semantics). Zero destination VGPRs.
__device__ __forceinline__ void gload_lds16(const ushort_t* g, ushort_t* l) {
  __builtin_amdgcn_global_load_lds(
      (const __attribute__((address_space(1))) unsigned int*)(g),
      (__attribute__((address_space(3))) unsigned int*)(l), 16, 0, 0);
}

// ---------------- CSR build: fixed-capacity two-level scatter ----------------
__global__ __launch_bounds__(256) void k_bin(const int* __restrict__ src,
                                             const int* __restrict__ dst,
                                             int* __restrict__ gbc,
                                             unsigned* __restrict__ ebuf) {
  __shared__ int hist[NBKT];
  int t = threadIdx.x;
  for (int i = t; i < NBKT; i += 256) hist[i] = 0;
  __syncthreads();
  int base = blockIdx.x * 4096;
  int s[16], d[16];
#pragma unroll
  for (int j = 0; j < 16; j++) {
    int e = base + j * 256 + t;
    if (e < EE) { s[j] = src[e]; d[j] = dst[e]; atomicAdd(&hist[d[j] >> 9], 1); }
    else d[j] = -1;
  }
  __syncthreads();
  for (int i = t; i < NBKT; i += 256) {
    int c = hist[i];
    hist[i] = c ? atomicAdd(&gbc[i], c) : 0;   // reserve in-bucket run
  }
  __syncthreads();
#pragma unroll
  for (int j = 0; j < 16; j++) {
    if (d[j] >= 0) {
      int bkt = d[j] >> 9;
      int pos = atomicAdd(&hist[bkt], 1);
      if (pos < CAP)                            // safety clamp (never hit here)
        ebuf[(size_t)bkt * CAP + pos] = (unsigned)s[j] | ((unsigned)(d[j] & 511) << 17);
    }
  }
}

// scan bucket counts -> ebase; rowptr[NN]=EE; zero BN stats
__global__ void k_bktscan(const int* __restrict__ gbc, int* __restrict__ ebase,
                          int* __restrict__ rowptr, float* __restrict__ stats) {
  __shared__ int sd[256];
  int t = threadIdx.x;
#pragma unroll
  for (int k = 0; k < 3; k++) stats[t + 256 * k] = 0.f;   // 768 floats
  int c = (t < NBKT) ? min(gbc[t], CAP) : 0;
  sd[t] = c; __syncthreads();
  for (int off = 1; off < 256; off <<= 1) {
    int x = 0;
    if (t >= off) x = sd[t - off];
    __syncthreads();
    sd[t] += x;
    __syncthreads();
  }
  if (t < NBKT) ebase[t] = sd[t] - c;          // exclusive
  if (t == NBKT - 1) rowptr[NN] = sd[t];       // == EE
}

// per bucket: LDS degree hist -> LDS scan -> rowptr + fine scatter (L2-resident window)
__global__ __launch_bounds__(256) void k_fine(const unsigned* __restrict__ ebuf,
                                              const int* __restrict__ gbc,
                                              const int* __restrict__ ebase,
                                              int* __restrict__ rowptr,
                                              int* __restrict__ csr) {
  __shared__ int dcur[512];
  __shared__ int sd[256];
  int b = blockIdx.x, t = threadIdx.x;
  int cnt = min(gbc[b], CAP);
  int eb = ebase[b];
  const unsigned* eb_p = ebuf + (size_t)b * CAP;
  dcur[t] = 0; dcur[t + 256] = 0;
  __syncthreads();
  for (int e = t; e < cnt; e += 256)
    atomicAdd(&dcur[(eb_p[e] >> 17) & 511], 1);
  __syncthreads();
  int a0 = dcur[2 * t], a1 = dcur[2 * t + 1];
  int ps = a0 + a1;
  sd[t] = ps; __syncthreads();
  for (int off = 1; off < 256; off <<= 1) {
    int x = 0;
    if (t >= off) x = sd[t - off];
    __syncthreads();
    sd[t] += x;
    __syncthreads();
  }
  int g0 = eb + sd[t] - ps;                    // global csr start for local node 2t
  dcur[2 * t] = g0; dcur[2 * t + 1] = g0 + a0;
  int n = (b << 9) + 2 * t;
  if (n < NN) rowptr[n] = g0;
  if (n + 1 < NN) rowptr[n + 1] = g0 + a0;
  __syncthreads();
  for (int e = t; e < cnt; e += 256) {
    unsigned v = eb_p[e];
    int pos = atomicAdd(&dcur[(v >> 17) & 511], 1);
    csr[pos] = (int)(v & 0x1FFFFu);
  }
}

// ---------------- merged prep: x->bf16 (blocks 0..6249) + W swizzle (6250..6261) ----
__global__ void k_prep(const float* __restrict__ x, ushort_t* __restrict__ hb,
                       const float* __restrict__ W1s, const float* __restrict__ W2s,
                       ushort_t* __restrict__ wf) {
  int b = blockIdx.x;
  if (b < 6250) {
    int i = b * 256 + threadIdx.x;   // each handles 4 elems of x
    f32x4 v = *(const f32x4*)(x + (size_t)i * 4);
    u16x4 o;
#pragma unroll
    for (int m = 0; m < 4; m++) o[m] = f2bf(v[m]);
    *(u16x4*)(hb + (size_t)i * 4) = o;
  } else {
    int gid = (b - 6250) * 256 + threadIdx.x;
    if (gid >= 3072) return;                  // 6 mats * 2u * 4t * 64 lanes
    int mat = gid >> 9, rem = gid & 511;
    int u = rem >> 8, t = (rem >> 6) & 3, lane = rem & 63;
    const float* W = ((mat & 1) ? W2s : W1s) + (mat >> 1) * 4096;
    ushort_t* o = wf + gid * 8;
#pragma unroll
    for (int j = 0; j < 8; j++) {
      int k = u * 32 + (lane >> 4) * 8 + j;
      int n = t * 16 + (lane & 15);
      o[j] = f2bf(W[k * 64 + n]);
    }
  }
}

// ---------------- fused aggregate + mlp1 (v4: LDS-DMA gather) ----------------
// 512 threads = 8 waves; block owns 64 nodes; 8-lane group owns ONE node.
// Rows gathered via global_load_lds (per-lane global addr, 0 dest VGPRs):
// per iteration, 4 instructions stage 4 edges/group (8 rows each, 4 KB/wave),
// one vmcnt(0) drain, ds_read_b128 back + accumulate in regs. Short-degree
// groups clamp the address to their own last edge (L1-hot, no extra traffic)
// and skip the accumulate. No atomics; no cross-wave sync in the loop.
__global__ __launch_bounds__(512) void k_aggmlp1(
    const ushort_t* __restrict__ hb, const int* __restrict__ rowptr,
    const int* __restrict__ csr, const ushort_t* __restrict__ wfrag,
    const float* __restrict__ b1, ushort_t* __restrict__ zb,
    float* __restrict__ stats) {
  __shared__ __align__(16) ushort_t stage[8 * 2048];  // 8 waves x 4KB; sw aliases
  __shared__ float lsum[64], lsq[64];
  ushort_t* sw = stage;                               // 64*72 ushorts after barrier
  int tid = threadIdx.x;
  if (tid < 64) lsum[tid] = 0.f;
  else if (tid < 128) lsq[tid - 64] = 0.f;
  int wv = tid >> 6, lane = tid & 63;
  int grp = lane >> 3, fl = lane & 7;
  int nl = wv * 8 + grp;                        // local node 0..63
  int node = blockIdx.x * 64 + nl;
  const ushort_t* hbase = hb + fl * 8;
  ushort_t* stgw = stage + wv * 2048;           // this wave's 4KB strip

  // ---- phase 1: gather ----
  f32x8 A = {0, 0, 0, 0, 0, 0, 0, 0};
  int e0 = 0, deg = 0;
  if (node < NN) {
    u16x8 sr = *(const u16x8*)(hbase + (size_t)node * 64);
#pragma unroll
    for (int m = 0; m < 8; m++) A[m] = bf2f(sr[m]);
    e0 = rowptr[node];
    deg = rowptr[node + 1] - e0;
  }
  // wave-uniform iteration count = max degree over the 8 groups
  int md = deg;
  md = max(md, __shfl_xor(md, 8));
  md = max(md, __shfl_xor(md, 16));
  md = max(md, __shfl_xor(md, 32));
  int niter = (md + 3) >> 2;
  int lq = fl & 3;
  for (int k = 0; k < niter; k++) {
    // group's next 4 csr indices (clamped); 2 lanes per index, broadcast read
    int li = (deg > 0) ? min(e0 + k * 4 + lq, e0 + deg - 1) : 0;
    int v = csr[li];
#pragma unroll
    for (int j = 0; j < 4; j++) {
      int sj = __shfl(v, (lane & 56) + j);      // group's edge-j src
      gload_lds16(hbase + (size_t)sj * 64, stgw + j * 512);
    }
    asm volatile("s_waitcnt vmcnt(0)" ::: "memory");
#pragma unroll
    for (int j = 0; j < 4; j++) {
      if (k * 4 + j < deg) {                    // group-uniform branch
        u16x8 rd = *(const u16x8*)(stgw + j * 512 + lane * 8);
#pragma unroll
        for (int m = 0; m < 8; m++) A[m] += bf2f(rd[m]);
      }
    }
  }
  __syncthreads();                              // all gathers done; stage -> sw
  {
    u16x8 o;
#pragma unroll
    for (int m = 0; m < 8; m++) o[m] = f2bf(A[m]);
    *(u16x8*)(sw + nl * 72 + fl * 8) = o;
  }
  __syncthreads();

  // ---- phase 2: MFMA on ALL 8 waves (16-row tile x 32-col half each) ----
  {
    int quad = lane >> 4, lo = lane & 15;
    int rt = wv >> 1, ch = wv & 1;
    int row0 = blockIdx.x * 64 + rt * 16;
    s16x8 bfr[2][2];
#pragma unroll
    for (int u = 0; u < 2; u++)
#pragma unroll
      for (int t2 = 0; t2 < 2; t2++)
        bfr[u][t2] = *(const s16x8*)(wfrag +
            (size_t)((u * 4 + ch * 2 + t2) * 64 + lane) * 8);

    f32x4 acc[2] = {};
#pragma unroll
    for (int u = 0; u < 2; u++) {
      bf16x8 af = *(const bf16x8*)(sw + (rt * 16 + lo) * 72 + u * 32 + quad * 8);
#pragma unroll
      for (int t2 = 0; t2 < 2; t2++)
        acc[t2] = __builtin_amdgcn_mfma_f32_16x16x32_bf16(
            af, __builtin_bit_cast(bf16x8, bfr[u][t2]), acc[t2], 0, 0, 0);
    }
    // C/D layout: col = (ch*2+t2)*16 + lo, row = row0 + quad*4 + r
#pragma unroll
    for (int t2 = 0; t2 < 2; t2++) {
      int col = (ch * 2 + t2) * 16 + lo;
      float bb = b1[col];
      float s1 = 0.f, s2 = 0.f;
#pragma unroll
      for (int r = 0; r < 4; r++) {
        int row = row0 + quad * 4 + r;
        if (row < NN) {
          float v = acc[t2][r] + bb;
          zb[(size_t)row * 64 + col] = f2bf(v);
          s1 += v; s2 += v * v;
        }
      }
      atomicAdd(&lsum[col], s1);
      atomicAdd(&lsq[col], s2);
    }
  }
  __syncthreads();
  if (tid < 64) {
    atomicAdd(&stats[tid], lsum[tid]);
    atomicAdd(&stats[64 + tid], lsq[tid]);
  }
}

// relu_out=1 (L0,L1): hb16 = relu( relu(zb*a+c)@W2 + b2 )
// relu_out=0 (L2):    h -> out+200000 (fp32) AND out[0..2N) = h@Wd + bd (fused decoder)
// BN finalize fused: each block computes a,c from raw sums (redundant, cheap).
__global__ __launch_bounds__(256) void k_mlp2(
    const ushort_t* __restrict__ zb, const float* __restrict__ stats,
    const float* __restrict__ gamma, const float* __restrict__ beta,
    const ushort_t* __restrict__ wfrag, const float* __restrict__ b2,
    ushort_t* __restrict__ hb, float* __restrict__ out,
    const float* __restrict__ Wd, const float* __restrict__ bd, int relu_out) {
  __shared__ __align__(16) ushort_t sw[64 * 72];
  __shared__ float abn[64], cbn[64];
  int tid = threadIdx.x;
  if (tid < 64) {   // fused BN finalize
    float inv = 1.f / (float)NN;
    float mu = stats[tid] * inv;
    float var = stats[64 + tid] * inv - mu * mu;
    float a = gamma[tid] * rsqrtf(var + BN_EPS);
    abn[tid] = a;
    cbn[tid] = beta[tid] - mu * a;
  }
  __syncthreads();
  {   // phase 1: BN affine + ReLU on bf16 z -> bf16 tile in LDS
    int r = tid >> 2, c0 = (tid & 3) * 16;
    size_t grow = (size_t)blockIdx.x * 64 + r;     // < NPAD; padded rows masked at store
#pragma unroll
    for (int jj = 0; jj < 16; jj += 8) {
      s16x8 zv = *(const s16x8*)(zb + grow * 64 + c0 + jj);
      f32x4 av0 = *(const f32x4*)(abn + c0 + jj);
      f32x4 av1 = *(const f32x4*)(abn + c0 + jj + 4);
      f32x4 cv0 = *(const f32x4*)(cbn + c0 + jj);
      f32x4 cv1 = *(const f32x4*)(cbn + c0 + jj + 4);
#pragma unroll
      for (int m = 0; m < 4; m++) {
        float v0 = fmaxf(bf2f((ushort_t)zv[m]) * av0[m] + cv0[m], 0.f);
        float v1 = fmaxf(bf2f((ushort_t)zv[m + 4]) * av1[m] + cv1[m], 0.f);
        sw[r * 72 + c0 + jj + m] = f2bf(v0);
        sw[r * 72 + c0 + jj + m + 4] = f2bf(v1);
      }
    }
  }
  __syncthreads();
  int wv = tid >> 6, lane = tid & 63;
  int quad = lane >> 4, lo = lane & 15;

  s16x8 bfr[2][4];
#pragma unroll
  for (int u = 0; u < 2; u++)
#pragma unroll
    for (int t = 0; t < 4; t++)
      bfr[u][t] = *(const s16x8*)(wfrag + (size_t)((u * 4 + t) * 64 + lane) * 8);

  f32x4 acc[4] = {};
#pragma unroll
  for (int u = 0; u < 2; u++) {
    bf16x8 af = *(const bf16x8*)(sw + (wv * 16 + lo) * 72 + u * 32 + quad * 8);
#pragma unroll
    for (int t = 0; t < 4; t++)
      acc[t] = __builtin_amdgcn_mfma_f32_16x16x32_bf16(
          af, __builtin_bit_cast(bf16x8, bfr[u][t]), acc[t], 0, 0, 0);
  }
  int row0 = blockIdx.x * 64 + wv * 16;
  float bbv[4];
#pragma unroll
  for (int t = 0; t < 4; t++) bbv[t] = b2[t * 16 + lo];

  if (relu_out) {
#pragma unroll
    for (int t = 0; t < 4; t++) {
      int col = t * 16 + lo;
#pragma unroll
      for (int r = 0; r < 4; r++) {
        int row = row0 + quad * 4 + r;
        if (row < NN)
          hb[(size_t)row * 64 + col] = f2bf(fmaxf(acc[t][r] + bbv[t], 0.f));
      }
    }
  } else {
    float* outh = out + (size_t)NN * 2;
    float wd0[4], wd1[4];
#pragma unroll
    for (int t = 0; t < 4; t++) {
      wd0[t] = Wd[(t * 16 + lo) * 2];
      wd1[t] = Wd[(t * 16 + lo) * 2 + 1];
    }
    float bd0 = bd[0], bd1 = bd[1];
#pragma unroll
    for (int t = 0; t < 4; t++) {
      int col = t * 16 + lo;
#pragma unroll
      for (int r = 0; r < 4; r++) {
        int row = row0 + quad * 4 + r;
        if (row < NN) outh[(size_t)row * 64 + col] = acc[t][r] + bbv[t];
      }
    }
#pragma unroll
    for (int r = 0; r < 4; r++) {
      float p0 = 0.f, p1 = 0.f;
#pragma unroll
      for (int t = 0; t < 4; t++) {
        float v = acc[t][r] + bbv[t];
        p0 += v * wd0[t]; p1 += v * wd1[t];
      }
#pragma unroll
      for (int o = 1; o < 16; o <<= 1) {   // reduce across the 16 lanes of the quad
        p0 += __shfl_xor(p0, o);
        p1 += __shfl_xor(p1, o);
      }
      int row = row0 + quad * 4 + r;
      if (lo == 0 && row < NN) {
        out[(size_t)row * 2 + 0] = p0 + bd0;
        out[(size_t)row * 2 + 1] = p1 + bd1;
      }
    }
  }
}

extern "C" void kernel_launch(void* const* d_in, const int* in_sizes, int n_in,
                              void* d_out, int out_size, void* d_ws, size_t ws_size,
                              hipStream_t stream) {
  (void)in_sizes; (void)n_in; (void)out_size; (void)ws_size;
  const float* x   = (const float*)d_in[0];
  const int*   ei  = (const int*)d_in[1];
  const float* W1s = (const float*)d_in[2];
  const float* b1s = (const float*)d_in[3];
  const float* gms = (const float*)d_in[4];
  const float* bts = (const float*)d_in[5];
  const float* W2s = (const float*)d_in[6];
  const float* b2s = (const float*)d_in[7];
  const float* Wd  = (const float*)d_in[8];
  const float* bd  = (const float*)d_in[9];
  float* out = (float*)d_out;
  const int* src = ei;
  const int* dst = ei + EE;

  char* w = (char*)d_ws;
  size_t off = 0;
  auto alloc = [&](size_t b) { char* p = w + off; off += (b + 255) & ~(size_t)255; return p; };
  ushort_t* zb     = (ushort_t*)alloc((size_t)NPAD * 64 * 2);   // 12.8 MB (ebuf aliases)
  ushort_t* hb16   = (ushort_t*)alloc((size_t)NPAD * 64 * 2);   // 12.8 MB bf16 rows
  int*      csr    = (int*)alloc((size_t)EE * 4);               // 6.4 MB
  int*      rowptr = (int*)alloc((size_t)(NN + 1) * 4);
  int*      gbc    = (int*)alloc((size_t)NBKT * 4);
  int*      ebase  = (int*)alloc((size_t)NBKT * 4);
  float*    stats  = (float*)alloc(768 * 4);                    // 3 x [sum|sq|spare]
  ushort_t* wf     = (ushort_t*)alloc((size_t)6 * 512 * 8 * 2); // swizzled W frags
  unsigned* ebuf   = (unsigned*)zb;  // 196*9216*4 = 7.2 MB, used pre-mlp only

  hipMemsetAsync(gbc, 0, (size_t)NBKT * 4, stream);
  k_bin    <<<(EE + 4095) / 4096, 256, 0, stream>>>(src, dst, gbc, ebuf);
  k_bktscan<<<1, 256, 0, stream>>>(gbc, ebase, rowptr, stats);
  k_fine   <<<NBKT, 256, 0, stream>>>(ebuf, gbc, ebase, rowptr, csr);
  k_prep   <<<6262, 256, 0, stream>>>(x, hb16, W1s, W2s, wf);

  for (int L = 0; L < 3; L++) {
    k_aggmlp1<<<(NN + 63) / 64, 512, 0, stream>>>(hb16, rowptr, csr,
                                                  wf + (size_t)(L * 2) * 4096,
                                                  b1s + L * 64, zb, stats + L * 256);
    k_mlp2<<<(NN + 63) / 64, 256, 0, stream>>>(zb, stats + L * 256,
                                               gms + L * 64, bts + L * 64,
                                               wf + (size_t)(L * 2 + 1) * 4096,
                                               b2s + L * 64, hb16, out, Wd, bd,
                                               (L < 2) ? 1 : 0);
  }
}